// Round 1
// baseline (493.813 us; speedup 1.0000x reference)
//
#include <hip/hip_runtime.h>

#define N_ROWS 16384
#define D_DIM  2048
#define BM 128
#define BN 128
#define BK 32
#define NKT (D_DIM / BK)   // 64 K-steps

typedef __attribute__((ext_vector_type(8))) _Float16 half8;
typedef __attribute__((ext_vector_type(4))) _Float16 half4_t;
typedef __attribute__((ext_vector_type(4))) float floatx4;

// ---------------------------------------------------------------------------
// Kernel 1: C = X * A^T + b, masked by (X[r][c] != 0), via fp16x2 split MFMA.
//   hi = (half)x ; lo = (half)((x - hi) * 4096)   [scale avoids fp16 denorms]
//   dot ≈ hi*hi + (hi*lo + lo*hi)/4096            [fp32-level accuracy]
// ---------------------------------------------------------------------------
__global__ __launch_bounds__(256, 2)
void gemm_mask_kernel(const float* __restrict__ X,
                      const float* __restrict__ A,
                      const float* __restrict__ bias,
                      float* __restrict__ out)
{
    __shared__ __align__(16) _Float16 sXh[2][BM * BK];
    __shared__ __align__(16) _Float16 sXl[2][BM * BK];
    __shared__ __align__(16) _Float16 sAh[2][BN * BK];
    __shared__ __align__(16) _Float16 sAl[2][BN * BK];

    const int t   = threadIdx.x;
    const int bid = blockIdx.x;

    // XCD-chunked tile swizzle: 2048 tiles, 8 XCDs -> 256 tiles each.
    // Within an XCD: column-major over (16 row-panels x 16 col-tiles) so
    // concurrent blocks share A col-panels (fit in 4 MiB L2).
    const int xcd    = bid & 7;
    const int local  = bid >> 3;          // 0..255
    const int r_tile = (xcd << 4) + (local & 15);
    const int c_tile = local >> 4;
    const int m0 = r_tile * BM;
    const int n0 = c_tile * BN;

    const int lane  = t & 63;
    const int w     = t >> 6;
    const int wr    = w >> 1;             // wave row 0..1 (64-row slab)
    const int wc    = w & 1;              // wave col 0..1 (64-col slab)
    const int lrow  = lane & 15;
    const int lslot = lane >> 4;          // 0..3 : which 8-half K-slot

    const float4* X4 = reinterpret_cast<const float4*>(X);
    const float4* A4 = reinterpret_cast<const float4*>(A);

    floatx4 acc1[4][4], acc2[4][4];
    #pragma unroll
    for (int mi = 0; mi < 4; ++mi)
        #pragma unroll
        for (int ni = 0; ni < 4; ++ni)
            #pragma unroll
            for (int j = 0; j < 4; ++j) { acc1[mi][ni][j] = 0.f; acc2[mi][ni][j] = 0.f; }

    float4 rx[4], ra[4];

    // staging map: float4 index f = i*256+t ; row = f>>3 ; k4 = f&7 (8 float4/row)
    #pragma unroll
    for (int i = 0; i < 4; ++i) {
        int f = i * 256 + t; int row = f >> 3; int k4 = f & 7;
        rx[i] = X4[(size_t)(m0 + row) * (D_DIM / 4) + k4];
        ra[i] = A4[(size_t)(n0 + row) * (D_DIM / 4) + k4];
    }

    // convert + swizzled LDS write. slot' = (k4>>1) ^ ((row>>1)&3)  (16B slots)
    auto stage = [&](int buf, const float4* rv, _Float16* dsh, _Float16* dsl) {
        #pragma unroll
        for (int i = 0; i < 4; ++i) {
            int f = i * 256 + t; int row = f >> 3; int k4 = f & 7;
            float4 v = rv[i];
            half4_t h, l;
            h[0] = (_Float16)v.x; h[1] = (_Float16)v.y;
            h[2] = (_Float16)v.z; h[3] = (_Float16)v.w;
            l[0] = (_Float16)((v.x - (float)h[0]) * 4096.0f);
            l[1] = (_Float16)((v.y - (float)h[1]) * 4096.0f);
            l[2] = (_Float16)((v.z - (float)h[2]) * 4096.0f);
            l[3] = (_Float16)((v.w - (float)h[3]) * 4096.0f);
            int off = row * BK + ((((k4 >> 1) ^ ((row >> 1) & 3)) << 3) + ((k4 & 1) << 2));
            *reinterpret_cast<half4_t*>(dsh + off) = h;
            *reinterpret_cast<half4_t*>(dsl + off) = l;
        }
        (void)buf;
    };

    stage(0, rx, &sXh[0][0], &sXl[0][0]);
    stage(0, ra, &sAh[0][0], &sAl[0][0]);

    int cur = 0;
    for (int kt = 0; kt < NKT; ++kt) {
        __syncthreads();
        const bool more = (kt + 1 < NKT);
        if (more) {
            int kb = (kt + 1) * (BK / 4);   // float4 col base
            #pragma unroll
            for (int i = 0; i < 4; ++i) {
                int f = i * 256 + t; int row = f >> 3; int k4 = f & 7;
                rx[i] = X4[(size_t)(m0 + row) * (D_DIM / 4) + kb + k4];
                ra[i] = A4[(size_t)(n0 + row) * (D_DIM / 4) + kb + k4];
            }
        }

        // B fragments (from A-tile): col = lrow, k-slot = lslot
        half8 bhf[4], blf[4];
        #pragma unroll
        for (int ni = 0; ni < 4; ++ni) {
            int row = wc * 64 + ni * 16 + lrow;
            int off = row * BK + ((lslot ^ ((row >> 1) & 3)) << 3);
            bhf[ni] = *reinterpret_cast<const half8*>(&sAh[cur][off]);
            blf[ni] = *reinterpret_cast<const half8*>(&sAl[cur][off]);
        }
        #pragma unroll
        for (int mi = 0; mi < 4; ++mi) {
            int row = wr * 64 + mi * 16 + lrow;
            int off = row * BK + ((lslot ^ ((row >> 1) & 3)) << 3);
            half8 ah = *reinterpret_cast<const half8*>(&sXh[cur][off]);
            half8 al = *reinterpret_cast<const half8*>(&sXl[cur][off]);
            #pragma unroll
            for (int ni = 0; ni < 4; ++ni) {
                acc1[mi][ni] = __builtin_amdgcn_mfma_f32_16x16x32_f16(ah, bhf[ni], acc1[mi][ni], 0, 0, 0);
                acc2[mi][ni] = __builtin_amdgcn_mfma_f32_16x16x32_f16(ah, blf[ni], acc2[mi][ni], 0, 0, 0);
                acc2[mi][ni] = __builtin_amdgcn_mfma_f32_16x16x32_f16(al, bhf[ni], acc2[mi][ni], 0, 0, 0);
            }
        }

        if (more) {
            int nxt = cur ^ 1;
            stage(nxt, rx, &sXh[nxt][0], &sXl[nxt][0]);
            stage(nxt, ra, &sAh[nxt][0], &sAl[nxt][0]);
            cur = nxt;
        }
    }

    // Epilogue: add bias, mask by X[r][c] != 0, write masked y_pred.
    // C/D layout: col = lane&15, row = (lane>>4)*4 + j   [m89-verified]
    #pragma unroll
    for (int mi = 0; mi < 4; ++mi) {
        #pragma unroll
        for (int ni = 0; ni < 4; ++ni) {
            int c = n0 + wc * 64 + ni * 16 + lrow;
            float bv = bias[c];
            #pragma unroll
            for (int j = 0; j < 4; ++j) {
                int r = m0 + wr * 64 + mi * 16 + lslot * 4 + j;
                float v = acc1[mi][ni][j] + acc2[mi][ni][j] * (1.0f / 4096.0f) + bv;
                float xv = X[(size_t)r * D_DIM + c];
                out[(size_t)r * D_DIM + c] = (xv != 0.0f) ? v : 0.0f;
            }
        }
    }
}

// ---------------------------------------------------------------------------
// Kernel 2: one wave per row -> inv[n] = row_sum != 0 ? 1/row_sum : 0
// (masked entries are already 0 in d_out, so a plain row sum is correct;
//  all-empty-mask rows give sum==0 -> inv 0 -> output row stays 0.)
// ---------------------------------------------------------------------------
__global__ void row_sum_inv_kernel(const float* __restrict__ out, float* __restrict__ inv)
{
    int gw = (blockIdx.x * 256 + threadIdx.x) >> 6;   // global wave = row
    int l  = threadIdx.x & 63;
    const float4* row = reinterpret_cast<const float4*>(out) + (size_t)gw * (D_DIM / 4);
    float s = 0.f;
    #pragma unroll
    for (int j = 0; j < 8; ++j) {
        float4 v = row[j * 64 + l];
        s += (v.x + v.y) + (v.z + v.w);
    }
    #pragma unroll
    for (int off = 32; off > 0; off >>= 1) s += __shfl_down(s, off, 64);
    if (l == 0) inv[gw] = (s != 0.0f) ? (1.0f / s) : 0.0f;
}

// ---------------------------------------------------------------------------
// Kernel 3: out[n,k] *= inv[n]
// ---------------------------------------------------------------------------
__global__ void scale_kernel(float* __restrict__ out, const float* __restrict__ inv)
{
    const int total = N_ROWS * (D_DIM / 4);
    float4* o = reinterpret_cast<float4*>(out);
    for (int i = blockIdx.x * blockDim.x + threadIdx.x; i < total;
         i += gridDim.x * blockDim.x) {
        float s  = inv[i >> 9];           // 512 float4 per row
        float4 v = o[i];
        v.x *= s; v.y *= s; v.z *= s; v.w *= s;
        o[i] = v;
    }
}

extern "C" void kernel_launch(void* const* d_in, const int* in_sizes, int n_in,
                              void* d_out, int out_size, void* d_ws, size_t ws_size,
                              hipStream_t stream)
{
    const float* X  = (const float*)d_in[0];
    const float* A  = (const float*)d_in[1];
    const float* b  = (const float*)d_in[2];
    float* out = (float*)d_out;
    float* inv = (float*)d_ws;            // 16384 floats = 64 KiB

    hipLaunchKernelGGL(gemm_mask_kernel, dim3((N_ROWS / BM) * (D_DIM / BN)), dim3(256), 0, stream,
                       X, A, b, out);
    hipLaunchKernelGGL(row_sum_inv_kernel, dim3(N_ROWS / 4), dim3(256), 0, stream, out, inv);
    hipLaunchKernelGGL(scale_kernel, dim3(2048), dim3(256), 0, stream, out, inv);
}